// Round 1
// 715.073 us; speedup vs baseline: 1.0358x; 1.0358x over previous
//
#include <hip/hip_runtime.h>
#include <hip/hip_bf16.h>
#include <cstdint>
#include <cstddef>

#define SEQ    4096
#define HEADS  32
#define HD     128
#define HIDDEN 2048
#define NINNER 4096
#define BLK    256
#define NB     16

typedef __attribute__((ext_vector_type(8)))  __bf16 bf16x8;
typedef __attribute__((ext_vector_type(4)))  __bf16 bf16x4;
typedef __attribute__((ext_vector_type(4)))  float  f32x4;

#define MFMA16(a,b,c) __builtin_amdgcn_mfma_f32_16x16x32_bf16((a),(b),(c),0,0,0)

typedef __attribute__((address_space(1))) const unsigned int gu32;
typedef __attribute__((address_space(3))) unsigned int lu32;

__device__ __forceinline__ void gld16(void* lds, const void* g){
    __builtin_amdgcn_global_load_lds((gu32*)g, (lu32*)lds, 16, 0, 0);
}

__device__ __forceinline__ float slope_for_head(int h){
    return exp2f(-0.25f*(float)(h+1)) * 1.00001f;
}

// ---------------------------------------------------------------- prep: cast hs + 3 weight transposes, one launch
__device__ __forceinline__ void tcast_block(const float* __restrict__ W, __bf16* __restrict__ Wt,
                                            int K, int N, int bx, int by, __bf16 (*t)[72], int tid){
    const int n0 = bx*64, k0 = by*64;
    const int r = tid >> 4, c4 = tid & 15;
    #pragma unroll
    for (int i = 0; i < 4; i++){
        int k = r + i*16;
        float4 v = *(const float4*)(W + (size_t)(k0 + k)*N + n0 + c4*4);
        t[c4*4+0][k] = (__bf16)v.x;
        t[c4*4+1][k] = (__bf16)v.y;
        t[c4*4+2][k] = (__bf16)v.z;
        t[c4*4+3][k] = (__bf16)v.w;
    }
    __syncthreads();
    #pragma unroll
    for (int j = 0; j < 2; j++){
        int idx = tid + j*256;
        int n = idx >> 3, c8 = idx & 7;
        bf16x8 val = *(const bf16x8*)&t[n][c8*8];
        *(bf16x8*)(Wt + (size_t)(n0 + n)*K + k0 + c8*8) = val;
    }
}

__global__ __launch_bounds__(256)
void prep_all(const float* __restrict__ hs, __bf16* __restrict__ hsb,
              const float* __restrict__ Wqkv, __bf16* __restrict__ WqkvT,
              const float* __restrict__ Wgate, __bf16* __restrict__ WgateT,
              const float* __restrict__ Wout, __bf16* __restrict__ WoutT)
{
    __shared__ __align__(16) __bf16 t[64][72];
    const int tid = threadIdx.x;
    int id = blockIdx.x;
    if (id < 8192){
        int i = (id*256 + tid)*4;
        float4 v = *(const float4*)(hs + i);
        bf16x4 o;
        o[0] = (__bf16)v.x; o[1] = (__bf16)v.y; o[2] = (__bf16)v.z; o[3] = (__bf16)v.w;
        *(bf16x4*)(hsb + i) = o;
    } else if (id < 14336){
        int j = id - 8192;
        tcast_block(Wqkv, WqkvT, 2048, 12288, j % 192, j / 192, t, tid);
    } else if (id < 16384){
        int j = id - 14336;
        tcast_block(Wgate, WgateT, 2048, 4096, j % 64, j / 64, t, tid);
    } else {
        int j = id - 16384;
        tcast_block(Wout, WoutT, 4096, 2048, j % 32, j / 32, t, tid);
    }
}

// ---------------------------------------------------------------- gemm_bt (128x128, 2-barrier) kept for W_out GEMM
template<int EPI>
__global__ __launch_bounds__(256,2)
void gemm_bt(const __bf16* __restrict__ A, const __bf16* __restrict__ Bt,
             float* __restrict__ Cf,
             int M, int N, int K)
{
    __shared__ __align__(16) __bf16 a_lds[128*64];
    __shared__ __align__(16) __bf16 b_lds[128*64];
    const int tid  = threadIdx.x;
    const int lane = tid & 63;
    const int w    = tid >> 6;
    const int lr   = lane & 15;
    const int quad = lane >> 4;
    const int wm = w & 1, wn = w >> 1;

    const int bm = blockIdx.x & 31;
    const int bn = blockIdx.x >> 5;

    f32x4 acc[4][4];
    #pragma unroll
    for (int i = 0; i < 4; i++)
        #pragma unroll
        for (int j = 0; j < 4; j++) acc[i][j] = (f32x4){0.f,0.f,0.f,0.f};

    const int r8 = lane >> 3;
    const int qs = (lane & 7) ^ r8;
    const int sw = lr & 7;
    const __bf16* Abase = A  + (size_t)bm*128*K;
    const __bf16* Bbase = Bt + (size_t)bn*128*K;

    for (int kb = 0; kb < K; kb += 64){
        #pragma unroll
        for (int t = 0; t < 4; t++){
            int ch = t*4 + w;
            gld16(a_lds + ch*512, Abase + (size_t)(ch*8 + r8)*K + kb + qs*8);
            gld16(b_lds + ch*512, Bbase + (size_t)(ch*8 + r8)*K + kb + qs*8);
        }
        __syncthreads();
        #pragma unroll
        for (int kk = 0; kk < 2; kk++){
            bf16x8 af[4];
            #pragma unroll
            for (int mt = 0; mt < 4; mt++)
                af[mt] = *(const bf16x8*)&a_lds[(wm*64 + mt*16 + lr)*64 + (((kk*4+quad) ^ sw)*8)];
            #pragma unroll
            for (int nt = 0; nt < 4; nt++){
                bf16x8 bfv = *(const bf16x8*)&b_lds[(wn*64 + nt*16 + lr)*64 + (((kk*4+quad) ^ sw)*8)];
                #pragma unroll
                for (int mt = 0; mt < 4; mt++)
                    acc[mt][nt] = MFMA16(af[mt], bfv, acc[mt][nt]);
            }
        }
        __syncthreads();
    }

    #pragma unroll
    for (int mt = 0; mt < 4; mt++)
    #pragma unroll
    for (int nt = 0; nt < 4; nt++)
    #pragma unroll
    for (int r = 0; r < 4; r++){
        int row = bm*128 + wm*64 + mt*16 + quad*4 + r;
        int col = bn*128 + wn*64 + nt*16 + lr;
        Cf[(size_t)row*N + col] = acc[mt][nt][r];
    }
}

// ---------------------------------------------------------------- fused qkv+gate GEMM: 256x256 tile, 8-wave, 8-phase
// M=4096, N=16384, K=2048. A [M][2048] bf16, Bt [N][2048] bf16.
//
// Schedule (T2+T3+T4+T5, learn_hip m201 pattern):
//   LDS = [A/B][2 buf][2 K-half][128 lds-rows x 64 bf16] = 128 KiB, 1 block/CU.
//   K-tile (BK=64) = 4 regions {A-kh0, B-kh0, A-kh1, B-kh1}, each 16 KB = 2 gld16/thread.
//   4 phases per K-tile t (buf c=t&1): ph0 (kk0,nt01) ph1 (kk0,nt23) ph2 (kk1,nt01) ph3 (kk1,nt23).
//   Each phase: ds_read frags; prefetch ONE region of tile t+1 into buf c^1; barrier;
//   lgkmcnt(0); setprio(1); 16 MFMA; setprio(0); [vmcnt]; barrier.
//   vmcnt ledger (per-wave, 2 loads/region, issue order A0B0A1B1 then per-phase):
//     before ph0 ds_reads, tile t needs its kh0 regions (issued t-1 ph0/ph1);
//       outstanding after them = t's kh1 (2+2)  -> vmcnt(4) at end of ph3.
//     before ph2 ds_reads, tile t needs its kh1 regions (issued t-1 ph2/ph3);
//       outstanding after them = t+1's kh0 (2+2) -> vmcnt(4) at end of ph1 (vmcnt(0) on last tile).
//   Never vmcnt(0) in steady state: prefetch stays in flight across barriers.
//
// LDS mapping (both-sides involution, rule #21): tile row R, k-granule g (8 elems):
//   lds_row = R>>1, slot = (((R&1)<<2)|g) ^ (lds_row & 7)   -> 64 lanes of a ds_read_b128
//   cover 1 KB of distinct contiguous LDS (2-way = free). Staging keeps LDS dest linear
//   (wave base + lane*16) and pre-swizzles the GLOBAL source address instead.
__global__ __launch_bounds__(512, 2)
void gemm_qkv(const __bf16* __restrict__ A, const __bf16* __restrict__ Bt,
              __bf16* __restrict__ qbuf, __bf16* __restrict__ kbuf,
              __bf16* __restrict__ kT,   __bf16* __restrict__ vT,
              __bf16* __restrict__ sgate)
{
    __shared__ __align__(16) __bf16 lds[2][2][2][8192];   // [A/B][buf][kh][128*64]

    const int tid  = threadIdx.x;
    const int lane = tid & 63;
    const int w    = tid >> 6;        // 0..7
    const int wm   = w & 1;           // M half (128 rows)
    const int wn   = w >> 1;          // 0..3   N quarter (64 cols)
    const int lr   = lane & 15;
    const int quad = lane >> 4;

    // grid 1024: XCD-chunked (bijective, 1024%8==0), bm fastest within an XCD's bn-stripe
    const int id  = blockIdx.x;
    const int wg  = (id & 7)*128 + (id >> 3);
    const int bm  = wg & 15;          // 0..15
    const int bn2 = wg >> 4;          // 0..63

    // staging source decode: lane l writes LDS bytes [ch*1024 + l*16); the content there must be
    // global[row = ch*16 + (l>>3)*2 + par][g], with ((par<<2)|g) = (l&7) ^ (l>>3).
    const int l3   = lane >> 3;
    const int lgs  = (lane & 7) ^ l3;
    const int srow = l3*2 + (lgs >> 2);
    const int sg   = lgs & 3;

    // ds_read offsets (elems): frag(row R, k-granule quad) lives at
    // (R>>1)*64 + ((((R&1)<<2)|quad) ^ ((R>>1)&7))*8 ; key (R>>1)&7 == (lr>>1)&7 for all mt/nt.
    const int ag   = ((((lane & 1) << 2) | quad) ^ ((lr >> 1) & 7)) * 8;
    const int aoff = (wm*64 + (lr >> 1))*64 + ag;   // + mt*512
    const int boff = (wn*32 + (lr >> 1))*64 + ag;   // + nt*512

    const __bf16* Abase = A  + (size_t)bm*256*2048;
    const __bf16* Bbase = Bt + (size_t)bn2*256*2048;

    auto stage = [&](int ab, int buf, int kh, const __bf16* Base, int tcol){
        #pragma unroll
        for (int j = 0; j < 2; j++){
            const int ch = j*8 + w;   // wave-uniform LDS base (global_load_lds requirement)
            gld16(&lds[ab][buf][kh][ch*512],
                  Base + (size_t)(ch*16 + srow)*2048 + tcol + kh*32 + sg*8);
        }
    };

    f32x4 acc[8][4];
    #pragma unroll
    for (int i = 0; i < 8; i++)
        #pragma unroll
        for (int j = 0; j < 4; j++) acc[i][j] = (f32x4){0.f,0.f,0.f,0.f};

    bf16x8 af[8], bf0, bf1;

    // prologue: tile 0 -> buf 0, kh0 regions first; wait kh0 (leave kh1's 4 loads in flight)
    stage(0, 0, 0, Abase, 0);
    stage(1, 0, 0, Bbase, 0);
    stage(0, 0, 1, Abase, 0);
    stage(1, 0, 1, Bbase, 0);
    asm volatile("s_waitcnt vmcnt(4)" ::: "memory");
    __builtin_amdgcn_s_barrier();

    for (int t = 0; t < 32; t++){
        const int c = t & 1, nbuf = c ^ 1;
        const bool pf = (t + 1 < 32);
        const int tcol = (t + 1)*64;

        // ---------------- phase 0: kk=0, nt={0,1}
        #pragma unroll
        for (int mt = 0; mt < 8; mt++)
            af[mt] = *(const bf16x8*)&lds[0][c][0][aoff + mt*512];
        bf0 = *(const bf16x8*)&lds[1][c][0][boff];
        bf1 = *(const bf16x8*)&lds[1][c][0][boff + 512];
        if (pf) stage(0, nbuf, 0, Abase, tcol);
        __builtin_amdgcn_s_barrier();
        asm volatile("s_waitcnt lgkmcnt(0)" ::: "memory");
        __builtin_amdgcn_s_setprio(1);
        #pragma unroll
        for (int mt = 0; mt < 8; mt++){
            acc[mt][0] = MFMA16(af[mt], bf0, acc[mt][0]);
            acc[mt][1] = MFMA16(af[mt], bf1, acc[mt][1]);
        }
        __builtin_amdgcn_s_setprio(0);
        __builtin_amdgcn_s_barrier();

        // ---------------- phase 1: kk=0, nt={2,3}
        bf0 = *(const bf16x8*)&lds[1][c][0][boff + 1024];
        bf1 = *(const bf16x8*)&lds[1][c][0][boff + 1536];
        if (pf) stage(1, nbuf, 0, Bbase, tcol);
        __builtin_amdgcn_s_barrier();
        asm volatile("s_waitcnt lgkmcnt(0)" ::: "memory");
        __builtin_amdgcn_s_setprio(1);
        #pragma unroll
        for (int mt = 0; mt < 8; mt++){
            acc[mt][2] = MFMA16(af[mt], bf0, acc[mt][2]);
            acc[mt][3] = MFMA16(af[mt], bf1, acc[mt][3]);
        }
        __builtin_amdgcn_s_setprio(0);
        if (pf) { asm volatile("s_waitcnt vmcnt(4)" ::: "memory"); }
        else    { asm volatile("s_waitcnt vmcnt(0)" ::: "memory"); }
        __builtin_amdgcn_s_barrier();

        // ---------------- phase 2: kk=1, nt={0,1}
        #pragma unroll
        for (int mt = 0; mt < 8; mt++)
            af[mt] = *(const bf16x8*)&lds[0][c][1][aoff + mt*512];
        bf0 = *(const bf16x8*)&lds[1][c][1][boff];
        bf1 = *(const bf16x8*)&lds[1][c][1][boff + 512];
        if (pf) stage(0, nbuf, 1, Abase, tcol);
        __builtin_amdgcn_s_barrier();
        asm volatile("s_waitcnt lgkmcnt(0)" ::: "memory");
        __builtin_amdgcn_s_setprio(1);
        #pragma unroll
        for (int mt = 0; mt < 8; mt++){
            acc[mt][0] = MFMA16(af[mt], bf0, acc[mt][0]);
            acc[mt][1] = MFMA16(af[mt], bf1, acc[mt][1]);
        }
        __builtin_amdgcn_s_setprio(0);
        __builtin_amdgcn_s_barrier();

        // ---------------- phase 3: kk=1, nt={2,3}
        bf0 = *(const bf16x8*)&lds[1][c][1][boff + 1024];
        bf1 = *(const bf16x8*)&lds[1][c][1][boff + 1536];
        if (pf) stage(1, nbuf, 1, Bbase, tcol);
        __builtin_amdgcn_s_barrier();
        asm volatile("s_waitcnt lgkmcnt(0)" ::: "memory");
        __builtin_amdgcn_s_setprio(1);
        #pragma unroll
        for (int mt = 0; mt < 8; mt++){
            acc[mt][2] = MFMA16(af[mt], bf0, acc[mt][2]);
            acc[mt][3] = MFMA16(af[mt], bf1, acc[mt][3]);
        }
        __builtin_amdgcn_s_setprio(0);
        asm volatile("s_waitcnt vmcnt(4)" ::: "memory");   // retire next tile's kh0 regions
        __builtin_amdgcn_s_barrier();
    }

    // ---------------- epilogue. C/D: col = lane&15, row = quad*4 + r.
    // Each wave is entirely inside one 128-col group: bn_old = bn2*2 + (wn>>1)  (== old 128-wide bn)
    const int bn_old = bn2*2 + (wn >> 1);
    const int dbase  = (wn & 1)*64;
    if (bn_old < 96){
        const int h = bn_old/3, which = bn_old - h*3;
        const float s = slope_for_head(h);
        if (which == 0){
            #pragma unroll
            for (int mt = 0; mt < 8; mt++){
                const int pos0 = bm*256 + wm*128 + mt*16 + quad*4;
                #pragma unroll
                for (int nt = 0; nt < 4; nt++){
                    const int d = dbase + nt*16 + lr;
                    #pragma unroll
                    for (int r = 0; r < 4; r++){
                        float x = acc[mt][nt][r];
                        qbuf[((size_t)h*SEQ + pos0 + r)*HD + d] = (__bf16)(x / (1.f + __expf(-x)));
                    }
                }
            }
        } else if (which == 1){
            const float es1 = __expf(s);
            #pragma unroll
            for (int mt = 0; mt < 8; mt++){
                const int pos0 = bm*256 + wm*128 + mt*16 + quad*4;
                const float dec0 = __expf(-s*(float)(255 - (pos0 & 255)));
                #pragma unroll
                for (int nt = 0; nt < 4; nt++){
                    const int d = dbase + nt*16 + lr;
                    float dec = dec0;
                    bf16x4 pk;
                    #pragma unroll
                    for (int r = 0; r < 4; r++){
                        float x = acc[mt][nt][r];
                        float sv = x / (1.f + __expf(-x));
                        kbuf[((size_t)h*SEQ + pos0 + r)*HD + d] = (__bf16)sv;
                        pk[r] = (__bf16)(sv*dec);
                        dec *= es1;
                    }
                    *(bf16x4*)(kT + ((size_t)h*HD + d)*SEQ + pos0) = pk;
                }
            }
        } else {
            #pragma unroll
            for (int mt = 0; mt < 8; mt++){
                const int pos0 = bm*256 + wm*128 + mt*16 + quad*4;
                #pragma unroll
                for (int nt = 0; nt < 4; nt++){
                    const int d = dbase + nt*16 + lr;
                    bf16x4 pv;
                    #pragma unroll
                    for (int r = 0; r < 4; r++){
                        float x = acc[mt][nt][r];
                        pv[r] = (__bf16)(x / (1.f + __expf(-x)));
                    }
                    *(bf16x4*)(vT + ((size_t)h*HD + d)*SEQ + pos0) = pv;
                }
            }
        }
    } else {
        const int col0 = (bn_old - 96)*128 + dbase;
        #pragma unroll
        for (int mt = 0; mt < 8; mt++){
            const int pos0 = bm*256 + wm*128 + mt*16 + quad*4;
            #pragma unroll
            for (int nt = 0; nt < 4; nt++){
                const int col = col0 + nt*16 + lr;
                #pragma unroll
                for (int r = 0; r < 4; r++){
                    float x = acc[mt][nt][r];
                    sgate[(size_t)(pos0 + r)*NINNER + col] = (__bf16)(1.f/(1.f + __expf(-x)));
                }
            }
        }
    }
}

// ---------------------------------------------------------------- pass A: kvbT[h][b][e][d] = sum_i v[i][e]*kdec[i][d]
__global__ __launch_bounds__(256,2)
void pass_a(const __bf16* __restrict__ vT, const __bf16* __restrict__ kT,
            float* __restrict__ kvbT)
{
    __shared__ __align__(16) __bf16 a_lds[128*64];
    __shared__ __align__(16) __bf16 b_lds[128*64];
    const int b = blockIdx.x, h = blockIdx.y;
    const int tid = threadIdx.x, lane = tid & 63, w = tid >> 6;
    const int lr = lane & 15, quad = lane >> 4;
    const int wm = w & 1, wn = w >> 1;

    f32x4 acc[4][4];
    #pragma unroll
    for (int i = 0; i < 4; i++)
        #pragma unroll
        for (int j = 0; j < 4; j++) acc[i][j] = (f32x4){0.f,0.f,0.f,0.f};

    const int r8 = lane >> 3;
    const int qs = (lane & 7) ^ r8;
    const int sw = lr & 7;
    const __bf16* Abase = vT + (size_t)h*HD*SEQ + (size_t)b*BLK;
    const __bf16* Bbase = kT + (size_t)h*HD*SEQ + (size_t)b*BLK;

    for (int kb = 0; kb < BLK; kb += 64){
        #pragma unroll
        for (int t = 0; t < 4; t++){
            int ch = t*4 + w;
            gld16(a_lds + ch*512, Abase + (size_t)(ch*8 + r8)*SEQ + kb + qs*8);
            gld16(b_lds + ch*512, Bbase + (size_t)(ch*8 + r8)*SEQ + kb + qs*8);
        }
        __syncthreads();
        #pragma unroll
        for (int kk = 0; kk < 2; kk++){
            bf16x8 af[4];
            #pragma unroll
            for (int mt = 0; mt < 4; mt++)
                af[mt] = *(const bf16x8*)&a_lds[(wm*64 + mt*16 + lr)*64 + (((kk*4+quad) ^ sw)*8)];
            #pragma unroll
            for (int nt = 0; nt < 4; nt++){
                bf16x8 bfv = *(const bf16x8*)&b_lds[(wn*64 + nt*16 + lr)*64 + (((kk*4+quad) ^ sw)*8)];
                #pragma unroll
                for (int mt = 0; mt < 4; mt++)
                    acc[mt][nt] = MFMA16(af[mt], bfv, acc[mt][nt]);
            }
        }
        __syncthreads();
    }
    float* outp = kvbT + (size_t)(h*NB + b)*HD*HD;
    #pragma unroll
    for (int mt = 0; mt < 4; mt++)
    #pragma unroll
    for (int nt = 0; nt < 4; nt++)
    #pragma unroll
    for (int r = 0; r < 4; r++){
        int row = wm*64 + mt*16 + quad*4 + r;   // e
        int col = wn*64 + nt*16 + lr;           // d
        outp[(size_t)row*HD + col] = acc[mt][nt][r];
    }
}

// ---------------------------------------------------------------- pass B: prefix scan (software-pipelined)
__global__ __launch_bounds__(256)
void scan_kv(const float* __restrict__ kvbT, const float* __restrict__ kv0,
             __bf16* __restrict__ kvsT)
{
    const int chunk = blockIdx.x;   // 0..7
    const int h = blockIdx.y;
    const int t = threadIdx.x;
    const float s = slope_for_head(h);
    const float lam = __expf(-s*(float)BLK);
    const int le0 = chunk*2048;
    float st[8], cur[8], nxt[8];
    #pragma unroll
    for (int j = 0; j < 8; j++){
        int le = le0 + t + 256*j;
        int e = le >> 7, d = le & 127;
        st[j] = kv0[(size_t)h*HD*HD + (size_t)d*HD + e];
    }
    size_t base0 = (size_t)(h*NB)*HD*HD + le0;
    #pragma unroll
    for (int j = 0; j < 8; j++) cur[j] = kvbT[base0 + t + 256*j];
    for (int b = 0; b < NB; b++){
        size_t base = (size_t)(h*NB + b)*HD*HD + le0;
        #pragma unroll
        for (int j = 0; j < 8; j++) kvsT[base + t + 256*j] = (__bf16)st[j];
        if (b < NB-1){
            size_t nb = base + (size_t)HD*HD;
            #pragma unroll
            for (int j = 0; j < 8; j++) nxt[j] = kvbT[nb + t + 256*j];
        }
        #pragma unroll
        for (int j = 0; j < 8; j++){ st[j] = lam*st[j] + cur[j]; cur[j] = nxt[j]; }
    }
}

// ---------------------------------------------------------------- pass C: out = (q*qdec)@kv + (diag_decay*(q@k^T))@v
__global__ __launch_bounds__(256,2)
void pass_c(const __bf16* __restrict__ qbuf, const __bf16* __restrict__ kbuf,
            const __bf16* __restrict__ vT, const __bf16* __restrict__ kvsT,
            float* __restrict__ attn)
{
    __shared__ __align__(16) __bf16 p_lds[4][32*72];
    const int rb = blockIdx.x & 1, b = blockIdx.x >> 1, h = blockIdx.y;
    const float s = slope_for_head(h);
    const int tid = threadIdx.x, lane = tid & 63, w = tid >> 6;
    const int lr = lane & 15, quad = lane >> 4;
    const int R0 = rb*128 + w*32;

    const __bf16* qh  = qbuf + (size_t)h*SEQ*HD + (size_t)b*BLK*HD;
    const __bf16* kh  = kbuf + (size_t)h*SEQ*HD + (size_t)b*BLK*HD;
    const __bf16* vh  = vT   + (size_t)h*HD*SEQ + (size_t)b*BLK;
    const __bf16* kvh = kvsT + (size_t)(h*NB + b)*HD*HD;

    f32x4 acc[2][8];
    #pragma unroll
    for (int i = 0; i < 2; i++)
        #pragma unroll
        for (int j = 0; j < 8; j++) acc[i][j] = (f32x4){0.f,0.f,0.f,0.f};

    bf16x8 qf[4][2];
    #pragma unroll
    for (int ks = 0; ks < 4; ks++)
        #pragma unroll
        for (int mt = 0; mt < 2; mt++)
            qf[ks][mt] = *(const bf16x8*)(qh + (size_t)(R0 + mt*16 + lr)*HD + ks*32 + quad*8);

    float qdec[2];
    #pragma unroll
    for (int mt = 0; mt < 2; mt++)
        qdec[mt] = __expf(-s*(float)(R0 + mt*16 + lr + 1));
    #pragma unroll
    for (int ks = 0; ks < 4; ks++){
        bf16x8 saf[2];
        #pragma unroll
        for (int mt = 0; mt < 2; mt++)
            #pragma unroll
            for (int j = 0; j < 8; j++) saf[mt][j] = (__bf16)((float)qf[ks][mt][j]*qdec[mt]);
        #pragma unroll
        for (int nt = 0; nt < 8; nt++){
            bf16x8 bv = *(const bf16x8*)(kvh + (size_t)(nt*16 + lr)*HD + ks*32 + quad*8);
            #pragma unroll
            for (int mt = 0; mt < 2; mt++) acc[mt][nt] = MFMA16(saf[mt], bv, acc[mt][nt]);
        }
    }

    float colf[4];
    #pragma unroll
    for (int nt = 0; nt < 4; nt++)
        colf[nt] = __expf(-s*(float)(63 - nt*16 - lr));
    const int cmax = (R0 + 31) >> 6;
    for (int c = 0; c <= cmax; c++){
        f32x4 qk[2][4];
        #pragma unroll
        for (int i = 0; i < 2; i++)
            #pragma unroll
            for (int j = 0; j < 4; j++) qk[i][j] = (f32x4){0.f,0.f,0.f,0.f};
        #pragma unroll
        for (int ks = 0; ks < 4; ks++){
            #pragma unroll
            for (int nt = 0; nt < 4; nt++){
                bf16x8 kf = *(const bf16x8*)(kh + (size_t)(c*64 + nt*16 + lr)*HD + ks*32 + quad*8);
                #pragma unroll
                for (int mt = 0; mt < 2; mt++) qk[mt][nt] = MFMA16(qf[ks][mt], kf, qk[mt][nt]);
            }
        }
        float rowf[2][4];
        #pragma unroll
        for (int mt = 0; mt < 2; mt++)
            #pragma unroll
            for (int r = 0; r < 4; r++)
                rowf[mt][r] = __expf(-s*(float)(R0 + mt*16 + quad*4 + r - c*64 - 63));
        #pragma unroll
        for (int mt = 0; mt < 2; mt++)
        #pragma unroll
        for (int nt = 0; nt < 4; nt++)
        #pragma unroll
        for (int r = 0; r < 4; r++){
            int i  = R0 + mt*16 + quad*4 + r;
            int jj = c*64 + nt*16 + lr;
            float dv = (i >= jj) ? rowf[mt][r]*colf[nt] : 0.f;
            p_lds[w][(mt*16 + quad*4 + r)*72 + nt*16 + lr] = (__bf16)(qk[mt][nt][r]*dv);
        }
        #pragma unroll
        for (int ks2 = 0; ks2 < 2; ks2++){
            bf16x8 pf[2];
            #pragma unroll
            for (int mt = 0; mt < 2; mt++)
                pf[mt] = *(const bf16x8*)&p_lds[w][(mt*16 + lr)*72 + ks2*32 + quad*8];
            #pragma unroll
            for (int nt = 0; nt < 8; nt++){
                bf16x8 vf = *(const bf16x8*)(vh + (size_t)(nt*16 + lr)*SEQ + c*64 + ks2*32 + quad*8);
                #pragma unroll
                for (int mt = 0; mt < 2; mt++) acc[mt][nt] = MFMA16(pf[mt], vf, acc[mt][nt]);
            }
        }
    }

    #pragma unroll
    for (int mt = 0; mt < 2; mt++)
    #pragma unroll
    for (int nt = 0; nt < 8; nt++)
    #pragma unroll
    for (int r = 0; r < 4; r++){
        int pos = b*BLK + R0 + mt*16 + quad*4 + r;
        int e = nt*16 + lr;
        attn[(size_t)pos*NINNER + h*HD + e] = acc[mt][nt][r];
    }
}

// ---------------------------------------------------------------- rmsnorm * sigmoid(gate) -> bf16
__global__ __launch_bounds__(256)
void rmsgate(const float* __restrict__ attn, const __bf16* __restrict__ sg,
             const float* __restrict__ nw, __bf16* __restrict__ h2)
{
    const int row = blockIdx.x, tid = threadIdx.x;
    const float* x = attn + (size_t)row*NINNER;
    float4 xs[4];
    float ss = 0.f;
    #pragma unroll
    for (int i = 0; i < 4; i++){
        xs[i] = *(const float4*)(x + (i*256 + tid)*4);
        ss += xs[i].x*xs[i].x + xs[i].y*xs[i].y + xs[i].z*xs[i].z + xs[i].w*xs[i].w;
    }
    #pragma unroll
    for (int o = 32; o > 0; o >>= 1) ss += __shfl_down(ss, o, 64);
    __shared__ float red[4];
    const int lane = tid & 63, w = tid >> 6;
    if (lane == 0) red[w] = ss;
    __syncthreads();
    float tot = red[0] + red[1] + red[2] + red[3];
    float rs = rsqrtf(tot*(1.f/NINNER) + 1e-5f);
    #pragma unroll
    for (int i = 0; i < 4; i++){
        int idx = (i*256 + tid)*4;
        float4 wv = *(const float4*)(nw + idx);
        bf16x4 sv = *(const bf16x4*)(sg + (size_t)row*NINNER + idx);
        bf16x4 o;
        o[0] = (__bf16)((float)sv[0] * xs[i].x*rs*wv.x);
        o[1] = (__bf16)((float)sv[1] * xs[i].y*rs*wv.y);
        o[2] = (__bf16)((float)sv[2] * xs[i].z*rs*wv.z);
        o[3] = (__bf16)((float)sv[3] * xs[i].w*rs*wv.w);
        *(bf16x4*)(h2 + (size_t)row*NINNER + idx) = o;
    }
}

// ================================================================ launch
extern "C" void kernel_launch(void* const* d_in, const int* in_sizes, int n_in,
                              void* d_out, int out_size, void* d_ws, size_t ws_size,
                              hipStream_t stream) {
    (void)in_sizes; (void)n_in; (void)out_size; (void)ws_size;
    const float* hs    = (const float*)d_in[0];
    const float* kv0   = (const float*)d_in[2];
    const float* Wqkv  = (const float*)d_in[3];
    const float* Wgate = (const float*)d_in[4];
    const float* Wout  = (const float*)d_in[5];
    const float* nw    = (const float*)d_in[6];
    float* out = (float*)d_out;

    char* ws = (char*)d_ws;
    __bf16* WqkvT  = (__bf16*)(ws);
    __bf16* WgateT = (__bf16*)(ws + 50331648);            // contiguous after WqkvT (fused GEMM weight)
    float*  attn   = (float*)(ws);                        // aliases weights after GEMMs consume them
    __bf16* WoutT  = (__bf16*)(ws + 67108864);
    __bf16* hsb    = (__bf16*)(ws + 83886080);
    __bf16* qkvb   = (__bf16*)(ws + 100663296);
    __bf16* qbuf   = qkvb;
    __bf16* kbuf   = qkvb + (size_t)HEADS*SEQ*HD;
    __bf16* h2     = qkvb;                                // alias q after pass_c
    __bf16* kT     = (__bf16*)(ws + 201326592);
    __bf16* vT     = (__bf16*)(ws + 234881024);
    float*  kvbT   = (float*) (ws + 268435456);
    __bf16* kvsT   = (__bf16*)(ws + 301989888);
    __bf16* sgate  = (__bf16*)(ws + 318767104);

    prep_all<<<18432, 256, 0, stream>>>(hs, hsb, Wqkv, WqkvT, Wgate, WgateT, Wout, WoutT);

    // fused qkv+gate GEMM (256x256 8-phase), epilogue writes q, k, kT(decayed), vT, sgate
    gemm_qkv<<<1024, 512, 0, stream>>>(hsb, WqkvT, qbuf, kbuf, kT, vT, sgate);

    pass_a<<<dim3(16, 32), 256, 0, stream>>>(vT, kT, kvbT);
    scan_kv<<<dim3(8, 32), 256, 0, stream>>>(kvbT, kv0, kvsT);
    pass_c<<<dim3(NB*2, 32), 256, 0, stream>>>(qbuf, kbuf, vT, kvsT, attn);

    rmsgate<<<4096, 256, 0, stream>>>(attn, sgate, nw, h2);
    gemm_bt<2><<<512, 256, 0, stream>>>(h2, WoutT, out, 4096, 2048, 4096);
}